// Round 10
// baseline (797.965 us; speedup 1.0000x reference)
//
#include <hip/hip_runtime.h>
#include <hip/hip_bf16.h>

#define B_ 4
#define P_ 1024
#define G_ 1024
#define L_ 2048
#define D_ 512
#define FF_ 2048
#define H_ 8
#define DH_ 64
#define LAYERS_ 4
#define LN_EPS_ 1e-5f

typedef __attribute__((ext_vector_type(8))) short bf16x8;
typedef __attribute__((ext_vector_type(4))) float f32x4;

__device__ __forceinline__ ushort f2b(float f) {
  unsigned u = __float_as_uint(f);
  unsigned r = (u + 0x7fffu + ((u >> 16) & 1u)) >> 16;
  return (ushort)r;
}
__device__ __forceinline__ float b2f(ushort u) {
  return __uint_as_float(((unsigned)u) << 16);
}

// async 16B global->LDS (DMA; dest = wave-uniform base + lane*16)
__device__ __forceinline__ void gld16(const ushort* g, ushort* l) {
  __builtin_amdgcn_global_load_lds(
      (const __attribute__((address_space(1))) void*)g,
      (__attribute__((address_space(3))) void*)l, 16, 0, 0);
}

// ---------------- concat pcpt+gen -> x (fp32) + xbf (bf16) ----------------
__global__ __launch_bounds__(256) void concat_kernel(const float* __restrict__ p,
    const float* __restrict__ g, float* __restrict__ x, ushort* __restrict__ xb)
{
  const int LD4 = L_*D_/4, PD4 = P_*D_/4;
  int i = blockIdx.x*256 + threadIdx.x;
  int b = i / LD4, r = i - b*LD4;
  float4 v;
  if (r < PD4) v = ((const float4*)p)[(size_t)b*PD4 + r];
  else         v = ((const float4*)g)[(size_t)b*PD4 + (r-PD4)];
  ((float4*)x)[i] = v;
  ushort4 h; h.x=f2b(v.x); h.y=f2b(v.y); h.z=f2b(v.z); h.w=f2b(v.w);
  ((ushort4*)xb)[i] = h;
}

// ---------------- writeout ----------------
__global__ __launch_bounds__(256) void writeout_kernel(const float* __restrict__ x,
    float* __restrict__ out)
{
  const int LD4 = L_*D_/4, PD4 = P_*D_/4, HALF = B_*PD4;
  int i = blockIdx.x*256 + threadIdx.x;
  int half = (i >= HALF) ? 1 : 0;
  int r = i - half*HALF;
  int b = r / PD4, q = r - b*PD4;
  ((float4*)out)[i] = ((const float4*)x)[(size_t)b*LD4 + half*PD4 + q];
}

// ---------------- weight transpose+convert: src K x N fp32 -> dst N x K bf16 ----------------
__global__ __launch_bounds__(256) void wconv_kernel(const float* __restrict__ src,
    ushort* __restrict__ dst, int K, int N)
{
  __shared__ float tile[32][33];
  int n0 = blockIdx.x*32, k0 = blockIdx.y*32, l = blockIdx.z;
  src += (size_t)l*K*N; dst += (size_t)l*K*N;
  int tx = threadIdx.x & 31, ty = threadIdx.x >> 5;
  #pragma unroll
  for (int u=0;u<4;++u) tile[ty+8*u][tx] = src[(size_t)(k0+ty+8*u)*N + n0+tx];
  __syncthreads();
  #pragma unroll
  for (int u=0;u<4;++u) dst[(size_t)(n0+ty+8*u)*K + k0+tx] = f2b(tile[tx][ty+8*u]);
}

// ---------------- bf16 MFMA GEMM, BN_ in {128,64}, BM=128, BK=64 ----------------
// LDS: 16B chunk c (0..7) of row r -> slot r*8 + (c ^ (r&7)); conflict-free.
template<int BN_, int RELU, int RES, int OUTBF>
__global__ __launch_bounds__(256) void mgemm(
    const ushort* __restrict__ A, const ushort* __restrict__ Bt,
    const float* __restrict__ bias, const float* __restrict__ res,
    void* __restrict__ Cout, int M, int N, int K)
{
  constexpr int MI = (BN_ == 128) ? 4 : 2;
  constexpr int BL = BN_ / 32;
  __shared__ ushort As[128*64];
  __shared__ ushort Bs[BN_*64];
  int t = threadIdx.x;
  int lane = t & 63, w = t >> 6;
  int wm = (BN_ == 128) ? (w >> 1) * 64 : w * 32;
  int wn = (BN_ == 128) ? (w & 1) * 64 : 0;
  int m0 = blockIdx.x * 128, n0 = blockIdx.y * BN_;

  f32x4 acc[MI][4] = {};

  int rbase = t >> 3;
  int cch   = (t & 7) ^ ((t >> 3) & 7);
  const ushort* Ag = A  + (size_t)(m0 + rbase)*K + cch*8;
  const ushort* Bg = Bt + (size_t)(n0 + rbase)*K + cch*8;
  ushort* Asl = As + t*8;
  ushort* Bsl = Bs + t*8;
  const size_t rowK32 = (size_t)32 * K;

  int fr = lane & 15, fq = lane >> 4;
  int swr[2];
  swr[0] = ((0*4 + fq) ^ (fr & 7)) * 8;
  swr[1] = ((1*4 + fq) ^ (fr & 7)) * 8;
  const ushort* Ard = As + (wm + fr)*64;
  const ushort* Brd = Bs + (wn + fr)*64;

  for (int k0 = 0; k0 < K; k0 += 64) {
    __syncthreads();
    #pragma unroll
    for (int L = 0; L < 4; ++L)  gld16(Ag + L*rowK32, Asl + L*2048);
    #pragma unroll
    for (int L = 0; L < BL; ++L) gld16(Bg + L*rowK32, Bsl + L*2048);
    Ag += 64; Bg += 64;
    __syncthreads();
    #pragma unroll
    for (int s = 0; s < 2; ++s) {
      int sw = swr[s];
      bf16x8 af[MI], bfr[4];
      #pragma unroll
      for (int i=0;i<MI;++i) af[i]  = *(const bf16x8*)(Ard + i*16*64 + sw);
      #pragma unroll
      for (int j=0;j<4;++j)  bfr[j] = *(const bf16x8*)(Brd + j*16*64 + sw);
      #pragma unroll
      for (int i=0;i<MI;++i)
        #pragma unroll
        for (int j=0;j<4;++j)
          acc[i][j] = __builtin_amdgcn_mfma_f32_16x16x32_bf16(af[i], bfr[j], acc[i][j], 0, 0, 0);
    }
  }

  int ncol = lane & 15;
  int rquad = (lane >> 4) * 4;
  #pragma unroll
  for (int j=0;j<4;++j) {
    int n = n0 + wn + j*16 + ncol;
    float bv = bias[n];
    #pragma unroll
    for (int i=0;i<MI;++i) {
      int mbase = m0 + wm + i*16 + rquad;
      #pragma unroll
      for (int r=0;r<4;++r) {
        int m = mbase + r;
        float c = acc[i][j][r] + bv;
        if (RES) c += res[(size_t)m*N + n];
        if (RELU) c = fmaxf(c, 0.f);
        if (OUTBF) ((ushort*)Cout)[(size_t)m*N + n] = f2b(c);
        else       ((float*)Cout)[(size_t)m*N + n] = c;
      }
    }
  }
}

// ---------------- split-K=2 GEMM (BN=64, fp32 partials; for W2) ----------------
__global__ __launch_bounds__(256) void mgemm_sk(
    const ushort* __restrict__ A, const ushort* __restrict__ Bt,
    const float* __restrict__ bias, float* __restrict__ C0,
    float* __restrict__ C1, int M, int N, int K)
{
  __shared__ ushort As[128*64];
  __shared__ ushort Bs[64*64];
  int t = threadIdx.x;
  int lane = t & 63, w = t >> 6;
  int wm = w * 32, wn = 0;
  int m0 = blockIdx.x * 128, n0 = blockIdx.y * 64;
  int slice = blockIdx.z;
  int Kh = K >> 1;
  const ushort* Ab = A  + slice*Kh;
  const ushort* Bb = Bt + slice*Kh;
  float* C = slice ? C1 : C0;

  f32x4 acc[2][4] = {};

  int rbase = t >> 3;
  int cch   = (t & 7) ^ ((t >> 3) & 7);
  const ushort* Ag = Ab + (size_t)(m0 + rbase)*K + cch*8;
  const ushort* Bg = Bb + (size_t)(n0 + rbase)*K + cch*8;
  ushort* Asl = As + t*8;
  ushort* Bsl = Bs + t*8;
  const size_t rowK32 = (size_t)32 * K;

  int fr = lane & 15, fq = lane >> 4;
  int swr[2];
  swr[0] = ((0*4 + fq) ^ (fr & 7)) * 8;
  swr[1] = ((1*4 + fq) ^ (fr & 7)) * 8;
  const ushort* Ard = As + (wm + fr)*64;
  const ushort* Brd = Bs + (wn + fr)*64;

  for (int k0 = 0; k0 < Kh; k0 += 64) {
    __syncthreads();
    #pragma unroll
    for (int L = 0; L < 4; ++L) gld16(Ag + L*rowK32, Asl + L*2048);
    #pragma unroll
    for (int L = 0; L < 2; ++L) gld16(Bg + L*rowK32, Bsl + L*2048);
    Ag += 64; Bg += 64;
    __syncthreads();
    #pragma unroll
    for (int s = 0; s < 2; ++s) {
      int sw = swr[s];
      bf16x8 af[2], bfr[4];
      #pragma unroll
      for (int i=0;i<2;++i) af[i]  = *(const bf16x8*)(Ard + i*16*64 + sw);
      #pragma unroll
      for (int j=0;j<4;++j) bfr[j] = *(const bf16x8*)(Brd + j*16*64 + sw);
      #pragma unroll
      for (int i=0;i<2;++i)
        #pragma unroll
        for (int j=0;j<4;++j)
          acc[i][j] = __builtin_amdgcn_mfma_f32_16x16x32_bf16(af[i], bfr[j], acc[i][j], 0, 0, 0);
    }
  }

  int ncol = lane & 15;
  int rquad = (lane >> 4) * 4;
  #pragma unroll
  for (int j=0;j<4;++j) {
    int n = n0 + wn + j*16 + ncol;
    float bv = slice ? 0.f : bias[n];
    #pragma unroll
    for (int i=0;i<2;++i) {
      int mbase = m0 + wm + i*16 + rquad;
      #pragma unroll
      for (int r=0;r<4;++r) {
        int m = mbase + r;
        C[(size_t)m*N + n] = acc[i][j][r] + bv;
      }
    }
  }
}

// ---------------- QKV GEMM (BK=64): bf16 out; q pre-scaled by 0.125*log2e ----------------
__global__ __launch_bounds__(256) void mgemm_qkv(
    const ushort* __restrict__ A,    // M x 512 bf16 (x)
    const ushort* __restrict__ Bt,   // 1536 x 512 bf16
    const float* __restrict__ bias,  // 1536
    ushort* __restrict__ qb,         // [b,h,l,64]  (pre-scaled)
    ushort* __restrict__ kb,         // [b,h,l,64]
    ushort* __restrict__ vtb)        // [b,h,64,l]
{
  const int K = D_;
  __shared__ ushort As[128*64];
  __shared__ ushort Bs[128*64];
  int t = threadIdx.x;
  int lane = t & 63, w = t >> 6;
  int wm = (w >> 1) * 64, wn = (w & 1) * 64;
  int m0 = blockIdx.x * 128, n0 = blockIdx.y * 128;

  f32x4 acc[4][4] = {};

  int rbase = t >> 3;
  int cch   = (t & 7) ^ ((t >> 3) & 7);
  const ushort* Ag = A  + (size_t)(m0 + rbase)*K + cch*8;
  const ushort* Bg = Bt + (size_t)(n0 + rbase)*K + cch*8;
  ushort* Asl = As + t*8;
  ushort* Bsl = Bs + t*8;
  const size_t rowK32 = (size_t)32 * K;

  int fr = lane & 15, fq = lane >> 4;
  int swr[2];
  swr[0] = ((0*4 + fq) ^ (fr & 7)) * 8;
  swr[1] = ((1*4 + fq) ^ (fr & 7)) * 8;
  const ushort* Ard = As + (wm + fr)*64;
  const ushort* Brd = Bs + (wn + fr)*64;

  for (int k0 = 0; k0 < K; k0 += 64) {
    __syncthreads();
    #pragma unroll
    for (int L = 0; L < 4; ++L) gld16(Ag + L*rowK32, Asl + L*2048);
    #pragma unroll
    for (int L = 0; L < 4; ++L) gld16(Bg + L*rowK32, Bsl + L*2048);
    Ag += 64; Bg += 64;
    __syncthreads();
    #pragma unroll
    for (int s = 0; s < 2; ++s) {
      int sw = swr[s];
      bf16x8 af[4], bfr[4];
      #pragma unroll
      for (int i=0;i<4;++i) af[i]  = *(const bf16x8*)(Ard + i*16*64 + sw);
      #pragma unroll
      for (int j=0;j<4;++j) bfr[j] = *(const bf16x8*)(Brd + j*16*64 + sw);
      #pragma unroll
      for (int i=0;i<4;++i)
        #pragma unroll
        for (int j=0;j<4;++j)
          acc[i][j] = __builtin_amdgcn_mfma_f32_16x16x32_bf16(af[i], bfr[j], acc[i][j], 0, 0, 0);
    }
  }

  int ncol = lane & 15;
  int rquad = (lane >> 4) * 4;
  #pragma unroll
  for (int j=0;j<4;++j) {
    int n = n0 + wn + j*16 + ncol;
    float bv = bias[n];
    int part = n >> 9;            // 0=q 1=k 2=v (block-uniform: 128 | 512)
    int wi = n & 511;
    int h = wi >> 6, d = wi & 63;
    #pragma unroll
    for (int i=0;i<4;++i) {
      int mbase = m0 + wm + i*16 + rquad;
      #pragma unroll
      for (int r=0;r<4;++r) {
        int m = mbase + r;
        int b = m >> 11, l = m & 2047;
        int bh = b*H_ + h;
        float cv = acc[i][j][r] + bv;
        if (part == 0) cv *= 0.18033688f;  // 1/sqrt(dh) * log2(e) folded into q
        ushort c = f2b(cv);
        if (part == 0)      qb[((size_t)bh*L_ + l)*DH_ + d] = c;
        else if (part == 1) kb[((size_t)bh*L_ + l)*DH_ + d] = c;
        else                vtb[((size_t)bh*DH_ + d)*L_ + l] = c;
      }
    }
  }
}

// ---------------- MFMA flash attention, one-pass softmax (exp2), swizzled LDS ----------------
// Tiles 64x64 ushorts, chunk c of row r at slot r*8 + (c ^ (r&7)).
__global__ __launch_bounds__(256) void attn_mfma(
    const ushort* __restrict__ qb, const ushort* __restrict__ kb,
    const ushort* __restrict__ vtb, ushort* __restrict__ outa)
{
  __shared__ ushort Qs[64*64];
  __shared__ ushort Ks[64*64];
  __shared__ ushort Vts[64*64];
  __shared__ ushort Ps[4*16*64];
  __shared__ float dls[64];

  int t = threadIdx.x;
  int lane = t & 63, w = t >> 6;
  int qt = blockIdx.x & 31;
  int h  = (blockIdx.x >> 5) & 7;
  int b  = blockIdx.x >> 8;
  int l0 = qt * 64;
  bool isgen = (l0 >= P_);
  int bh = b*H_ + h;

  const ushort* qg  = qb  + ((size_t)bh*L_ + l0)*DH_;
  const ushort* kgb = kb  + (size_t)bh*L_*DH_;
  const ushort* vtg = vtb + (size_t)bh*DH_*L_;

  int sr = t >> 3;                    // 0..31
  int ct = t & 7;                     // global chunk
  int gcol = ct * 8;
  int scol = (ct ^ (sr & 7)) * 8;     // swizzled LDS col; (sr+32)&7 == sr&7

  {
    uint4 x0 = *(const uint4*)(qg + (size_t)sr*DH_ + gcol);
    uint4 x1 = *(const uint4*)(qg + (size_t)(sr+32)*DH_ + gcol);
    *(uint4*)(Qs + sr*64 + scol) = x0;
    *(uint4*)(Qs + (sr+32)*64 + scol) = x1;
  }
  __syncthreads();

  int fr = lane & 15, fq = lane >> 4;
  int fsw[2];
  fsw[0] = ((0*4 + fq) ^ (fr & 7)) * 8;
  fsw[1] = ((1*4 + fq) ^ (fr & 7)) * 8;
  bf16x8 qf[2];
  qf[0] = *(const bf16x8*)(Qs + (16*w + fr)*64 + fsw[0]);
  qf[1] = *(const bf16x8*)(Qs + (16*w + fr)*64 + fsw[1]);

  float den[4] = {0.f, 0.f, 0.f, 0.f};
  f32x4 o[4] = {};

  ushort* Pw = Ps + w*16*64;

  // register prefetch of K/V tile kt=0
  uint4 pk0 = *(const uint4*)(kgb + (size_t)sr*DH_ + gcol);
  uint4 pk1 = *(const uint4*)(kgb + (size_t)(sr+32)*DH_ + gcol);
  uint4 pv0 = *(const uint4*)(vtg + (size_t)sr*L_ + gcol);
  uint4 pv1 = *(const uint4*)(vtg + (size_t)(sr+32)*L_ + gcol);

  for (int kt = 0; kt < 16; ++kt) {
    __syncthreads();
    *(uint4*)(Ks + sr*64 + scol) = pk0;
    *(uint4*)(Ks + (sr+32)*64 + scol) = pk1;
    *(uint4*)(Vts + sr*64 + scol) = pv0;
    *(uint4*)(Vts + (sr+32)*64 + scol) = pv1;
    __syncthreads();

    if (kt < 15) {
      int p1 = (kt + 1) * 64;
      pk0 = *(const uint4*)(kgb + (size_t)(p1+sr)*DH_ + gcol);
      pk1 = *(const uint4*)(kgb + (size_t)(p1+sr+32)*DH_ + gcol);
      pv0 = *(const uint4*)(vtg + (size_t)sr*L_ + p1 + gcol);
      pv1 = *(const uint4*)(vtg + (size_t)(sr+32)*L_ + p1 + gcol);
    }

    f32x4 sc4[4] = {};
    #pragma unroll
    for (int s=0;s<2;++s) {
      #pragma unroll
      for (int j=0;j<4;++j) {
        bf16x8 kf = *(const bf16x8*)(Ks + (j*16 + fr)*64 + fsw[s]);
        sc4[j] = __builtin_amdgcn_mfma_f32_16x16x32_bf16(qf[s], kf, sc4[j], 0, 0, 0);
      }
    }

    // one-pass softmax in base-2 (q pre-scaled by log2e)
    #pragma unroll
    for (int r=0;r<4;++r) {
      float e0 = exp2f(sc4[0][r]);
      float e1 = exp2f(sc4[1][r]);
      float e2 = exp2f(sc4[2][r]);
      float e3 = exp2f(sc4[3][r]);
      den[r] += (e0+e1) + (e2+e3);
      int rr = fq*4 + r;
      int rx = (rr & 7);
      // col 16j+fr -> chunk 2j + (fr>>3), within fr&7
      int wi = fr & 7, hi = fr >> 3;
      Pw[rr*64 + (((0 + hi) ^ rx)*8) + wi] = (ushort)(__float_as_uint(e0) >> 16);
      Pw[rr*64 + (((2 + hi) ^ rx)*8) + wi] = (ushort)(__float_as_uint(e1) >> 16);
      Pw[rr*64 + (((4 + hi) ^ rx)*8) + wi] = (ushort)(__float_as_uint(e2) >> 16);
      Pw[rr*64 + (((6 + hi) ^ rx)*8) + wi] = (ushort)(__float_as_uint(e3) >> 16);
    }
    asm volatile("s_waitcnt lgkmcnt(0)" ::: "memory");

    #pragma unroll
    for (int s=0;s<2;++s) {
      bf16x8 pf = *(const bf16x8*)(Pw + fr*64 + fsw[s]);
      #pragma unroll
      for (int j=0;j<4;++j) {
        bf16x8 vf = *(const bf16x8*)(Vts + (j*16 + fr)*64 + fsw[s]);
        o[j] = __builtin_amdgcn_mfma_f32_16x16x32_bf16(pf, vf, o[j], 0, 0, 0);
      }
    }
  }

  #pragma unroll
  for (int r=0;r<4;++r) {
    float d = den[r];
    d += __shfl_xor(d, 1, 16);
    d += __shfl_xor(d, 2, 16);
    d += __shfl_xor(d, 4, 16);
    d += __shfl_xor(d, 8, 16);
    den[r] = d;
  }

  if (isgen) {
    __syncthreads();
    {
      uint4 k0v = *(const uint4*)(kgb + (size_t)(l0+sr)*DH_ + gcol);
      uint4 k1v = *(const uint4*)(kgb + (size_t)(l0+sr+32)*DH_ + gcol);
      uint4 v0v = *(const uint4*)(vtg + (size_t)sr*L_ + l0 + gcol);
      uint4 v1v = *(const uint4*)(vtg + (size_t)(sr+32)*L_ + l0 + gcol);
      *(uint4*)(Ks + sr*64 + scol) = k0v;
      *(uint4*)(Ks + (sr+32)*64 + scol) = k1v;
      *(uint4*)(Vts + sr*64 + scol) = v0v;
      *(uint4*)(Vts + (sr+32)*64 + scol) = v1v;
    }
    __syncthreads();
    {
      int row = t >> 2, part = t & 3;
      int rx = row & 7;
      float dsum = 0.f;
      #pragma unroll
      for (int u=0;u<16;++u) {
        int d = part*16 + u;
        int idx = row*64 + (((d>>3) ^ rx)*8) + (d&7);
        dsum = fmaf(b2f(Qs[idx]), b2f(Ks[idx]), dsum);   // q pre-scaled (log2 units)
      }
      dsum += __shfl_xor(dsum, 1, 4);
      dsum += __shfl_xor(dsum, 2, 4);
      if (part == 0) dls[row] = dsum;
    }
    __syncthreads();
    #pragma unroll
    for (int r=0;r<4;++r) {
      int rr = 16*w + fq*4 + r;
      float ed = exp2f(dls[rr]);
      den[r] += ed;
      #pragma unroll
      for (int j=0;j<4;++j) {
        float vv = b2f(Vts[(j*16 + fr)*64 + (((rr>>3) ^ (fr & 7))*8) + (rr & 7)]);
        o[j][r] += ed*vv;
      }
    }
  }

  #pragma unroll
  for (int r=0;r<4;++r) {
    float inv = 1.f / den[r];
    int l = l0 + 16*w + fq*4 + r;
    #pragma unroll
    for (int j=0;j<4;++j)
      outa[((size_t)b*L_ + l)*D_ + h*DH_ + j*16 + fr] = f2b(o[j][r]*inv);
  }
}

// ---------------- LayerNorm -> x fp32 + xbf bf16 ----------------
__global__ __launch_bounds__(64) void ln_kernel(const float* __restrict__ y,
    const float* __restrict__ gw, const float* __restrict__ bw,
    float* __restrict__ x, ushort* __restrict__ xb)
{
  int row = blockIdx.x, t = threadIdx.x;
  const float4* yr = (const float4*)(y + (size_t)row*D_);
  float4 v0 = yr[t], v1 = yr[t+64];
  float s = v0.x+v0.y+v0.z+v0.w + v1.x+v1.y+v1.z+v1.w;
  for (int off=32; off>0; off>>=1) s += __shfl_down(s, off, 64);
  s = __shfl(s, 0, 64);
  float mu = s * (1.f/D_);
  float dx;
  float q = 0.f;
  dx=v0.x-mu; q+=dx*dx; dx=v0.y-mu; q+=dx*dx; dx=v0.z-mu; q+=dx*dx; dx=v0.w-mu; q+=dx*dx;
  dx=v1.x-mu; q+=dx*dx; dx=v1.y-mu; q+=dx*dx; dx=v1.z-mu; q+=dx*dx; dx=v1.w-mu; q+=dx*dx;
  for (int off=32; off>0; off>>=1) q += __shfl_down(q, off, 64);
  q = __shfl(q, 0, 64);
  float rinv = rsqrtf(q*(1.f/D_) + LN_EPS_);
  const float4* g4 = (const float4*)gw;
  const float4* b4 = (const float4*)bw;
  float4 gv0=g4[t], gv1=g4[t+64], bv0=b4[t], bv1=b4[t+64];
  float4 o0, o1;
  o0.x=(v0.x-mu)*rinv*gv0.x+bv0.x; o0.y=(v0.y-mu)*rinv*gv0.y+bv0.y;
  o0.z=(v0.z-mu)*rinv*gv0.z+bv0.z; o0.w=(v0.w-mu)*rinv*gv0.w+bv0.w;
  o1.x=(v1.x-mu)*rinv*gv1.x+bv1.x; o1.y=(v1.y-mu)*rinv*gv1.y+bv1.y;
  o1.z=(v1.z-mu)*rinv*gv1.z+bv1.z; o1.w=(v1.w-mu)*rinv*gv1.w+bv1.w;
  float4* xr = (float4*)(x + (size_t)row*D_);
  xr[t]=o0; xr[t+64]=o1;
  ushort4 h0, h1;
  h0.x=f2b(o0.x); h0.y=f2b(o0.y); h0.z=f2b(o0.z); h0.w=f2b(o0.w);
  h1.x=f2b(o1.x); h1.y=f2b(o1.y); h1.z=f2b(o1.z); h1.w=f2b(o1.w);
  ushort4* xbr = (ushort4*)(xb + (size_t)row*D_);
  xbr[t]=h0; xbr[t+64]=h1;
}

// ---------------- LN over y0+y1+xres (split-K combine) ----------------
__global__ __launch_bounds__(64) void ln2_kernel(const float* __restrict__ y0,
    const float* __restrict__ y1, const float* __restrict__ xres,
    const float* __restrict__ gw, const float* __restrict__ bw,
    float* __restrict__ x, ushort* __restrict__ xb)
{
  int row = blockIdx.x, t = threadIdx.x;
  const float4* a4 = (const float4*)(y0 + (size_t)row*D_);
  const float4* c4 = (const float4*)(y1 + (size_t)row*D_);
  const float4* r4 = (const float4*)(xres + (size_t)row*D_);
  float4 v0 = a4[t], v1 = a4[t+64];
  float4 u0 = c4[t], u1 = c4[t+64];
  float4 w0 = r4[t], w1 = r4[t+64];
  v0.x+=u0.x+w0.x; v0.y+=u0.y+w0.y; v0.z+=u0.z+w0.z; v0.w+=u0.w+w0.w;
  v1.x+=u1.x+w1.x; v1.y+=u1.y+w1.y; v1.z+=u1.z+w1.z; v1.w+=u1.w+w1.w;
  float s = v0.x+v0.y+v0.z+v0.w + v1.x+v1.y+v1.z+v1.w;
  for (int off=32; off>0; off>>=1) s += __shfl_down(s, off, 64);
  s = __shfl(s, 0, 64);
  float mu = s * (1.f/D_);
  float dx;
  float q = 0.f;
  dx=v0.x-mu; q+=dx*dx; dx=v0.y-mu; q+=dx*dx; dx=v0.z-mu; q+=dx*dx; dx=v0.w-mu; q+=dx*dx;
  dx=v1.x-mu; q+=dx*dx; dx=v1.y-mu; q+=dx*dx; dx=v1.z-mu; q+=dx*dx; dx=v1.w-mu; q+=dx*dx;
  for (int off=32; off>0; off>>=1) q += __shfl_down(q, off, 64);
  q = __shfl(q, 0, 64);
  float rinv = rsqrtf(q*(1.f/D_) + LN_EPS_);
  const float4* g4 = (const float4*)gw;
  const float4* b4 = (const float4*)bw;
  float4 gv0=g4[t], gv1=g4[t+64], bv0=b4[t], bv1=b4[t+64];
  float4 o0, o1;
  o0.x=(v0.x-mu)*rinv*gv0.x+bv0.x; o0.y=(v0.y-mu)*rinv*gv0.y+bv0.y;
  o0.z=(v0.z-mu)*rinv*gv0.z+bv0.z; o0.w=(v0.w-mu)*rinv*gv0.w+bv0.w;
  o1.x=(v1.x-mu)*rinv*gv1.x+bv1.x; o1.y=(v1.y-mu)*rinv*gv1.y+bv1.y;
  o1.z=(v1.z-mu)*rinv*gv1.z+bv1.z; o1.w=(v1.w-mu)*rinv*gv1.w+bv1.w;
  float4* xr = (float4*)(x + (size_t)row*D_);
  xr[t]=o0; xr[t+64]=o1;
  ushort4 h0, h1;
  h0.x=f2b(o0.x); h0.y=f2b(o0.y); h0.z=f2b(o0.z); h0.w=f2b(o0.w);
  h1.x=f2b(o1.x); h1.y=f2b(o1.y); h1.z=f2b(o1.z); h1.w=f2b(o1.w);
  ushort4* xbr = (ushort4*)(xb + (size_t)row*D_);
  xbr[t]=h0; xbr[t+64]=h1;
}

extern "C" void kernel_launch(void* const* d_in, const int* in_sizes, int n_in,
                              void* d_out, int out_size, void* d_ws, size_t ws_size,
                              hipStream_t stream) {
  const float* pcpt = (const float*)d_in[0];
  const float* gen  = (const float*)d_in[1];
  const float* Wqkv = (const float*)d_in[3];
  const float* bqkv = (const float*)d_in[4];
  const float* Wo   = (const float*)d_in[5];
  const float* bo   = (const float*)d_in[6];
  const float* W1   = (const float*)d_in[7];
  const float* b1   = (const float*)d_in[8];
  const float* W2   = (const float*)d_in[9];
  const float* b2   = (const float*)d_in[10];
  const float* g1   = (const float*)d_in[11];
  const float* be1  = (const float*)d_in[12];
  const float* g2   = (const float*)d_in[13];
  const float* be2  = (const float*)d_in[14];
  float* out = (float*)d_out;

  const size_t XD  = (size_t)B_*L_*D_;
  const size_t HKV = (size_t)B_*H_*L_*DH_;
  const size_t HFF = (size_t)B_*L_*FF_;

  float*  xbuf = (float*)d_ws;
  ushort* xbf  = (ushort*)(xbuf + XD);
  ushort* region = xbf + XD;
  ushort* qb  = region;                        // aliased with hbf
  ushort* kb  = region + HKV;
  ushort* vtb = region + 2*HKV;
  ushort* hbf = region;
  ushort* abf = region + HFF;
  ushort* wb  = abf + XD;
  ushort* wqkv_b = wb;
  ushort* wo_b   = wqkv_b + (size_t)4*3*D_*D_;
  ushort* w1_b   = wo_b   + (size_t)4*D_*D_;
  ushort* w2_b   = w1_b   + (size_t)4*FF_*D_;
  float*  ypart1 = (float*)(w2_b + (size_t)4*D_*FF_);  // split-K partial (16 MB)
  float*  ybuf = out;                                   // partial 0 / Wo y

  const int M = B_*L_;

  wconv_kernel<<<dim3(3*D_/32, D_/32, 4), 256, 0, stream>>>(Wqkv, wqkv_b, D_, 3*D_);
  wconv_kernel<<<dim3(D_/32,   D_/32, 4), 256, 0, stream>>>(Wo,   wo_b,   D_, D_);
  wconv_kernel<<<dim3(FF_/32,  D_/32, 4), 256, 0, stream>>>(W1,   w1_b,   D_, FF_);
  wconv_kernel<<<dim3(D_/32,  FF_/32, 4), 256, 0, stream>>>(W2,   w2_b,   FF_, D_);

  concat_kernel<<<4096, 256, 0, stream>>>(pcpt, gen, xbuf, xbf);

  for (int i = 0; i < LAYERS_; ++i) {
    const ushort* wqkv_i = wqkv_b + (size_t)i*3*D_*D_;
    const ushort* wo_i   = wo_b   + (size_t)i*D_*D_;
    const ushort* w1_i   = w1_b   + (size_t)i*FF_*D_;
    const ushort* w2_i   = w2_b   + (size_t)i*D_*FF_;
    const float* bqkv_i = bqkv + (size_t)i*3*D_;
    const float* bo_i   = bo   + (size_t)i*D_;
    const float* b1_i   = b1   + (size_t)i*FF_;
    const float* b2_i   = b2   + (size_t)i*D_;
    const float* g1_i   = g1   + (size_t)i*D_;
    const float* be1_i  = be1  + (size_t)i*D_;
    const float* g2_i   = g2   + (size_t)i*D_;
    const float* be2_i  = be2  + (size_t)i*D_;

    mgemm_qkv<<<dim3(M/128, 3*D_/128), 256, 0, stream>>>(
        xbf, wqkv_i, bqkv_i, qb, kb, vtb);

    attn_mfma<<<B_*H_*(L_/64), 256, 0, stream>>>(qb, kb, vtb, abf);

    mgemm<64,0,1,0><<<dim3(M/128, D_/64), 256, 0, stream>>>(
        abf, wo_i, bo_i, xbuf, ybuf, M, D_, D_);

    ln_kernel<<<M, 64, 0, stream>>>(ybuf, g1_i, be1_i, xbuf, xbf);

    mgemm<128,1,0,1><<<dim3(M/128, FF_/128), 256, 0, stream>>>(
        xbf, w1_i, b1_i, nullptr, hbf, M, FF_, D_);

    // W2 split-K=2: partials to ybuf / ypart1, combined in ln2
    mgemm_sk<<<dim3(M/128, D_/64, 2), 256, 0, stream>>>(
        hbf, w2_i, b2_i, ybuf, ypart1, M, D_, FF_);

    ln2_kernel<<<M, 64, 0, stream>>>(ybuf, ypart1, xbuf, g2_i, be2_i, xbuf, xbf);
  }

  writeout_kernel<<<4096, 256, 0, stream>>>(xbuf, out);
}